// Round 4
// baseline (721.230 us; speedup 1.0000x reference)
//
#include <hip/hip_runtime.h>
#include <hip/hip_bf16.h>

#define SEQ 4096
#define DIMC 2048
#define NH 16
#define DHD 128

typedef short s8v __attribute__((ext_vector_type(8)));
typedef float f4v __attribute__((ext_vector_type(4)));
typedef __bf16 bf8 __attribute__((ext_vector_type(8)));
typedef float f4 __attribute__((ext_vector_type(4)));
typedef float f16v __attribute__((ext_vector_type(16)));
typedef int i4v __attribute__((ext_vector_type(4)));

typedef __attribute__((address_space(3))) void lds_t;
typedef __attribute__((address_space(1))) void gbl_t;

// Static device scratch (112 MiB). No d_ws dependence.
__device__ __attribute__((aligned(256))) short g_h[(size_t)SEQ * DIMC];
__device__ __attribute__((aligned(256))) short g_q[(size_t)SEQ * DIMC];
__device__ __attribute__((aligned(256))) short g_k[(size_t)SEQ * DIMC];
__device__ __attribute__((aligned(256))) short g_v[(size_t)SEQ * DIMC];
__device__ __attribute__((aligned(256))) short g_vt[(size_t)DIMC * SEQ];     // [h*128+d][s]
__device__ __attribute__((aligned(256))) short g_wt[4][(size_t)DIMC * DIMC]; // [n][k]

__device__ __forceinline__ float b2f(short s) {
    union { unsigned u; float f; } v;
    v.u = ((unsigned)(unsigned short)s) << 16;
    return v.f;
}
__device__ __forceinline__ short f2b(float f) {
    union { float f; unsigned u; } v;
    v.f = f;
    unsigned b = v.u;
    b += 0x7FFFu + ((b >> 16) & 1u);   // RNE
    return (short)(b >> 16);
}
__device__ __forceinline__ f4 mfma16(bf8 a, bf8 b, f4 c) {
    return __builtin_amdgcn_mfma_f32_16x16x32_bf16(a, b, c, 0, 0, 0);
}
__device__ __forceinline__ f16v mfma32(bf8 a, bf8 b, f16v c) {
    return __builtin_amdgcn_mfma_f32_32x32x16_bf16(a, b, c, 0, 0, 0);
}
__device__ __forceinline__ void gl_lds16(const short* g, short* l) {
    __builtin_amdgcn_global_load_lds((gbl_t*)g, (lds_t*)l, 16, 0, 0);
}
// v_permlane32_swap_b32: a' = [a_lo, b_lo], b' = [a_hi, b_hi] (32-lane halves)
__device__ __forceinline__ void plane32_swap(int& a, int& b) {
    asm volatile("v_permlane32_swap_b32 %0, %1" : "+v"(a), "+v"(b));
}
// packed f32 pair -> one u32 of 2x bf16 (RNE), T12 recipe (no builtin on gfx950)
__device__ __forceinline__ int pk2b(float a, float b) {
    int r;
    asm("v_cvt_pk_bf16_f32 %0, %1, %2" : "=v"(r) : "v"(a), "v"(b));
    return r;
}

// ---------------- hidden f32 -> g_h bf16 ----------------
__global__ __launch_bounds__(256) void conv_h(const float* __restrict__ src) {
    size_t i = ((size_t)blockIdx.x * 256 + threadIdx.x) * 8;
    f4v u0 = *reinterpret_cast<const f4v*>(src + i);
    f4v u1 = *reinterpret_cast<const f4v*>(src + i + 4);
    s8v t;
    for (int j = 0; j < 4; ++j) { t[j] = f2b(u0[j]); t[4 + j] = f2b(u1[j]); }
    *reinterpret_cast<s8v*>(g_h + i) = t;
}

// ---------------- W f32 [k][n] -> g_wt[z] bf16 [n][k] ----------------
__global__ __launch_bounds__(256) void prep_w(const float* __restrict__ W0,
                                              const float* __restrict__ W1,
                                              const float* __restrict__ W2,
                                              const float* __restrict__ W3) {
    __shared__ __attribute__((aligned(16))) float t[64][68];
    const int z = blockIdx.z;
    const float* W = (z == 0) ? W0 : (z == 1) ? W1 : (z == 2) ? W2 : W3;
    short* WT = g_wt[z];
    const int r0 = blockIdx.y * 64, c0 = blockIdx.x * 64;   // r=k, c=n
    const int tid = threadIdx.x;
    for (int i = 0; i < 4; ++i) {
        int slot = tid + i * 256;
        int r = slot >> 4, c4 = (slot & 15) * 4;
        *reinterpret_cast<f4v*>(&t[r][c4]) =
            *reinterpret_cast<const f4v*>(&W[(size_t)(r0 + r) * DIMC + c0 + c4]);
    }
    __syncthreads();
    for (int i = 0; i < 2; ++i) {
        int slot = tid + i * 256;
        int n = slot >> 3, k8 = (slot & 7) * 8;
        s8v o;
        for (int j = 0; j < 8; ++j) o[j] = f2b(t[k8 + j][n]);
        *reinterpret_cast<s8v*>(&WT[(size_t)(c0 + n) * DIMC + r0 + k8]) = o;
    }
}

// ---------------- shared GEMM body (m97-style: global_load_lds staging) ------
template <int DSTF>
__device__ __forceinline__ void gemm_body(const short* __restrict__ X,
                                          const short* __restrict__ Bw,
                                          const float* __restrict__ bias,
                                          short* __restrict__ Yb,
                                          float* __restrict__ Yf,
                                          int bm, int bn) {
    __shared__ __attribute__((aligned(16))) short As[128 * 32];
    __shared__ __attribute__((aligned(16))) short Bs[128 * 32];
    const int tid = threadIdx.x;
    const int w = tid >> 6, lane = tid & 63;
    const int l16 = lane & 15, quad = lane >> 4;
    const int wm = w & 1, wn = w >> 1;

    f4 acc[4][4];
    for (int mi = 0; mi < 4; ++mi)
        for (int ni = 0; ni < 4; ++ni) acc[mi][ni] = (f4)0.0f;

    const int s0 = tid, s1 = tid + 256;
    const int ra0 = s0 >> 2, ca0 = (s0 & 3) * 8;
    const int ra1 = s1 >> 2, ca1 = (s1 & 3) * 8;
    const size_t xo0 = (size_t)(bm * 128 + ra0) * DIMC + ca0;
    const size_t xo1 = (size_t)(bm * 128 + ra1) * DIMC + ca1;
    const size_t bo0 = (size_t)(bn * 128 + ra0) * DIMC + ca0;
    const size_t bo1 = (size_t)(bn * 128 + ra1) * DIMC + ca1;
    short* lda0 = As + (size_t)(0 * 256 + w * 64) * 8;
    short* lda1 = As + (size_t)(1 * 256 + w * 64) * 8;
    short* ldb0 = Bs + (size_t)(0 * 256 + w * 64) * 8;
    short* ldb1 = Bs + (size_t)(1 * 256 + w * 64) * 8;

    for (int kb = 0; kb < DIMC; kb += 32) {
        __syncthreads();
        gl_lds16(X + xo0 + kb, lda0);
        gl_lds16(X + xo1 + kb, lda1);
        gl_lds16(Bw + bo0 + kb, ldb0);
        gl_lds16(Bw + bo1 + kb, ldb1);
        __syncthreads();
        bf8 af[4], bfr[4];
        for (int mi = 0; mi < 4; ++mi)
            af[mi] = *reinterpret_cast<const bf8*>(As + (wm * 64 + mi * 16 + l16) * 32 + quad * 8);
        for (int ni = 0; ni < 4; ++ni)
            bfr[ni] = *reinterpret_cast<const bf8*>(Bs + (wn * 64 + ni * 16 + l16) * 32 + quad * 8);
        for (int mi = 0; mi < 4; ++mi)
            for (int ni = 0; ni < 4; ++ni)
                acc[mi][ni] = mfma16(af[mi], bfr[ni], acc[mi][ni]);
    }

    for (int ni = 0; ni < 4; ++ni) {
        int col = bn * 128 + wn * 64 + ni * 16 + l16;
        float bcol = bias[col];
        for (int mi = 0; mi < 4; ++mi) {
            int row = bm * 128 + wm * 64 + mi * 16 + quad * 4;
            for (int r = 0; r < 4; ++r) {
                if (DSTF)
                    Yf[(size_t)(row + r) * DIMC + col] = acc[mi][ni][r] + bcol;
                else
                    Yb[(size_t)(row + r) * DIMC + col] = f2b(acc[mi][ni][r] + bcol);
            }
        }
    }
}

__global__ __launch_bounds__(256, 2) void gemm_qkv(const float* __restrict__ bq,
                                                   const float* __restrict__ bk,
                                                   const float* __restrict__ bv) {
    const int z = blockIdx.z;
    const float* bias = (z == 0) ? bq : (z == 1) ? bk : bv;
    short* Y = (z == 0) ? g_q : (z == 1) ? g_k : g_v;
    gemm_body<0>(g_h, g_wt[z], bias, Y, nullptr, blockIdx.y, blockIdx.x);
}

__global__ __launch_bounds__(256, 2) void gemm_o(const float* __restrict__ bias,
                                                 float* __restrict__ Yf) {
    gemm_body<1>(g_q, g_wt[3], bias, nullptr, Yf, blockIdx.y, blockIdx.x);
}

// ---------------- fused RMSNorm + RoPE, in place on g_q/g_k ------
// q pre-scaled by log2(e)/sqrt(DHD) (folded attn scale + exp2 conversion).
__global__ __launch_bounds__(256) void rmsnorm_rope(const float* __restrict__ gq,
                                                    const float* __restrict__ gk,
                                                    const float* __restrict__ fc,
                                                    const float* __restrict__ fs) {
    __shared__ float partial[4];
    __shared__ float totsh;
    const int s = blockIdx.x;
    const int which = blockIdx.y;
    short* x = which ? g_k : g_q;
    const float* g = which ? gk : gq;
    const int tid = threadIdx.x;
    const int d0 = tid * 8;

    s8v xv = *reinterpret_cast<const s8v*>(&x[(size_t)s * DIMC + d0]);
    float xf[8];
    float ssq = 0.0f;
    for (int j = 0; j < 8; ++j) { xf[j] = b2f(xv[j]); ssq += xf[j] * xf[j]; }
    for (int off = 32; off; off >>= 1) ssq += __shfl_down(ssq, off);
    if ((tid & 63) == 0) partial[tid >> 6] = ssq;
    __syncthreads();
    if (tid == 0) totsh = partial[0] + partial[1] + partial[2] + partial[3];
    __syncthreads();
    float rs = rsqrtf(totsh * (1.0f / (float)DIMC) + 1e-5f);
    if (which == 0) rs *= 0.12751744f;   // log2(e)/sqrt(128)

    f4v g0 = *reinterpret_cast<const f4v*>(&g[d0]);
    f4v g1 = *reinterpret_cast<const f4v*>(&g[d0 + 4]);
    float xn[8];
    for (int j = 0; j < 4; ++j) { xn[j] = xf[j] * rs * g0[j]; xn[4 + j] = xf[4 + j] * rs * g1[j]; }

    s8v ov;
    for (int p = 0; p < 4; ++p) {
        int e = d0 + 2 * p;
        int hd = e & (DHD - 1);
        float c = fc[(size_t)s * DHD + hd];
        float sn = fs[(size_t)s * DHD + hd + 1];
        float x1 = xn[2 * p], x2 = xn[2 * p + 1];
        ov[2 * p]     = f2b(x1 * c - x2 * sn);
        ov[2 * p + 1] = f2b(x1 * sn + x2 * c);
    }
    *reinterpret_cast<s8v*>(&x[(size_t)s * DIMC + d0]) = ov;
}

// ---------------- V transpose: g_v [s][h*128+d] -> g_vt [h*128+d][s] ----------------
__global__ __launch_bounds__(256) void transpose_v() {
    __shared__ __attribute__((aligned(16))) short t[64][72];
    const int h = blockIdx.z, dt = blockIdx.y, st = blockIdx.x;
    const int tid = threadIdx.x;
    const short* src = g_v + (size_t)st * 64 * DIMC + h * DHD + dt * 64;
    for (int i = 0; i < 2; ++i) {
        int slot = tid + i * 256;
        int s = slot >> 3, d8 = (slot & 7) * 8;
        *reinterpret_cast<s8v*>(&t[s][d8]) =
            *reinterpret_cast<const s8v*>(src + (size_t)s * DIMC + d8);
    }
    __syncthreads();
    short* dst = g_vt + (size_t)(h * DHD + dt * 64) * SEQ + st * 64;
    for (int i = 0; i < 2; ++i) {
        int slot = tid + i * 256;
        int d = slot >> 3, s8_ = (slot & 7) * 8;
        s8v o;
        for (int j = 0; j < 8; ++j) o[j] = t[s8_ + j][d];
        *reinterpret_cast<s8v*>(dst + (size_t)d * SEQ + s8_) = o;
    }
}

// ---------------- flash attention, 8-wave blocks, key-split waves ------------
// 512 threads = 8 waves: wq = w&3 picks the 32-q sub-block (q-tile 128),
// wk = w>>2 picks the 32-key half of each 64-key tile. Same 64 KB LDS as the
// 4-wave version -> 2 blocks/CU x 8 waves = 4 waves/SIMD (2x occupancy).
// Swapped QK^T (mfma32(K,Q), q = lane&31), in-register softmax via
// v_cvt_pk_bf16_f32 + permlane32_swap (T12), ones-MFMA row-sum, double-
// buffered K/V with counted vmcnt. Key-halves combined via a one-time LDS
// epilogue (reuses staging buffers, lane-symmetric, conflict-free).
__global__ __launch_bounds__(512, 4) void attn_k() {
    __shared__ __attribute__((aligned(16))) short Ks0[2][64 * 128];   // [buf][key][dh], cb rotated by key
    __shared__ __attribute__((aligned(16))) short Vt0[2][128 * 64];   // [buf][dh][key], kb rotated by dh

    const int h = blockIdx.y;
    const int q0 = blockIdx.x * 128;
    const int tid = threadIdx.x;
    const int w = tid >> 6, lane = tid & 63;
    const int wq = w & 3, wk = w >> 2;
    const int l32 = lane & 31, hf = lane >> 5;
    const int l16 = lane & 15;
    const int cbase = hf + l16;        // K read: cs = (dc*2 + cbase) & 15
    const int khl = hf + l32;          // V read: ks = (wk*4 + kp2*2 + khl) & 7

    // Q B-frags: qf[dc] = Q[q = q0+wq*32+l32][d = dc*16 + hf*8 .. +7]
    bf8 qf[8];
    {
        const short* qb = g_q + (size_t)(q0 + wq * 32 + l32) * DIMC + h * DHD + hf * 8;
#pragma unroll
        for (int dc = 0; dc < 8; ++dc)
            qf[dc] = *reinterpret_cast<const bf8*>(qb + dc * 16);
    }

    f16v of[4];
#pragma unroll
    for (int i = 0; i < 4; ++i) of[i] = (f16v)0.0f;
    f16v lacc = (f16v)0.0f;
    const f16v fz = (f16v)0.0f;

    s8v ob;
#pragma unroll
    for (int j = 0; j < 8; ++j) ob[j] = (short)0x3F80;   // bf16 1.0
    const bf8 vones = __builtin_bit_cast(bf8, ob);

    const short* Kbase = g_k + h * DHD;
    const short* Vbase = g_vt + (size_t)h * DHD * SEQ;

    const short* kp[2];
    const short* vp[2];
#pragma unroll
    for (int i = 0; i < 2; ++i) {
        int s = tid + i * 512;
        int krow = s >> 4, kcb = ((s & 15) - krow) & 15;   // rotated global cb
        int vd = s >> 3, vkb = ((s & 7) - vd) & 7;         // rotated global kb
        kp[i] = Kbase + (size_t)krow * DIMC + kcb * 8;
        vp[i] = Vbase + (size_t)vd * SEQ + vkb * 8;
    }

    // prologue: stage tile 0 into buffer 0 (4 loads/lane in flight)
#pragma unroll
    for (int i = 0; i < 2; ++i) {
        gl_lds16(kp[i], &Ks0[0][(size_t)(i * 512 + w * 64) * 8]);
        kp[i] += (size_t)64 * DIMC;
    }
#pragma unroll
    for (int i = 0; i < 2; ++i) {
        gl_lds16(vp[i], &Vt0[0][(size_t)(i * 512 + w * 64) * 8]);
        vp[i] += 64;
    }

    for (int kt = 0; kt < SEQ; kt += 64) {
        const int cur = (kt >> 6) & 1;
        // stage tile t+1 into the other buffer, then wait ONLY tile t's loads
        if (kt + 64 < SEQ) {
            const int nxt = cur ^ 1;
#pragma unroll
            for (int i = 0; i < 2; ++i) {
                gl_lds16(kp[i], &Ks0[nxt][(size_t)(i * 512 + w * 64) * 8]);
                kp[i] += (size_t)64 * DIMC;
            }
#pragma unroll
            for (int i = 0; i < 2; ++i) {
                gl_lds16(vp[i], &Vt0[nxt][(size_t)(i * 512 + w * 64) * 8]);
                vp[i] += 64;
            }
            asm volatile("s_waitcnt vmcnt(4)" ::: "memory");
        } else {
            asm volatile("s_waitcnt vmcnt(0)" ::: "memory");
        }
        __builtin_amdgcn_sched_barrier(0);
        __builtin_amdgcn_s_barrier();   // all waves' tile-t loads landed
        __builtin_amdgcn_sched_barrier(0);

        const short* Ks = Ks0[cur];
        const short* Vt = Vt0[cur];

        // ---- swapped QK^T for this wave's key-half: D[key = wk*32+map][q = l32]
        const short* krb = Ks + (wk * 32 + l32) * 128;
        __builtin_amdgcn_s_setprio(1);
        f16v sa = mfma32(*reinterpret_cast<const bf8*>(krb + ((cbase & 15) << 3)), qf[0], fz);
#pragma unroll
        for (int dc = 1; dc < 8; ++dc) {
            bf8 kf = *reinterpret_cast<const bf8*>(krb + (((dc * 2 + cbase) & 15) << 3));
            sa = mfma32(kf, qf[dc], sa);
        }
        __builtin_amdgcn_s_setprio(0);

        // ---- p = exp2(s), pack pairs to bf16 words
        int wv[8];
#pragma unroll
        for (int t = 0; t < 8; ++t) {
            float e0 = exp2f(sa[2 * t]);
            float e1 = exp2f(sa[2 * t + 1]);
            wv[t] = pk2b(e0, e1);
        }
        // ---- cross-half redistribution -> PV A-frags (16 keys each)
        int a0 = wv[0], b0 = wv[2]; plane32_swap(a0, b0);
        int a1 = wv[1], b1 = wv[3]; plane32_swap(a1, b1);
        int a2 = wv[4], b2 = wv[6]; plane32_swap(a2, b2);
        int a3 = wv[5], b3 = wv[7]; plane32_swap(a3, b3);
        i4v pw0 = {a0, a1, b0, b1};
        i4v pw1 = {a2, a3, b2, b3};
        bf8 pa0 = __builtin_bit_cast(bf8, pw0);
        bf8 pa1 = __builtin_bit_cast(bf8, pw1);

        __builtin_amdgcn_s_setprio(1);
        // ---- l += P . 1 (rows align with of)
        lacc = mfma32(pa0, vones, lacc);
        lacc = mfma32(pa1, vones, lacc);

        // ---- P V: of[dcb] over d = dcb*32 + l32; keys chunk wk*2+kp2
#pragma unroll
        for (int kp2 = 0; kp2 < 2; ++kp2) {
            bf8 pa = kp2 ? pa1 : pa0;
#pragma unroll
            for (int dcb = 0; dcb < 4; ++dcb) {
                int d = dcb * 32 + l32;
                int ks = (wk * 4 + kp2 * 2 + khl) & 7;
                bf8 vf = *reinterpret_cast<const bf8*>(Vt + d * 64 + ks * 8);
                of[dcb] = mfma32(pa, vf, of[dcb]);
            }
        }
        __builtin_amdgcn_s_setprio(0);

        __builtin_amdgcn_s_barrier();   // all reads of buf[cur] done before re-stage
        __builtin_amdgcn_sched_barrier(0);
    }

    // ---- epilogue: combine key-halves via LDS (reuse staging buffers) ----
    __syncthreads();
    float* pO = (float*)(&Ks0[0][0]);   // 32 KB: [wq][d2][r][lane]
    float* pL = (float*)(&Vt0[0][0]);   // 16 KB: [wq][r][lane]
    if (wk == 1) {
#pragma unroll
        for (int r = 0; r < 16; ++r)
            pL[(wq * 16 + r) * 64 + lane] = lacc[r];
    }
#pragma unroll
    for (int halfd = 0; halfd < 2; ++halfd) {
        if (wk == 1) {
#pragma unroll
            for (int d2 = 0; d2 < 2; ++d2)
#pragma unroll
                for (int r = 0; r < 16; ++r)
                    pO[((wq * 2 + d2) * 16 + r) * 64 + lane] = of[halfd * 2 + d2][r];
        }
        __syncthreads();
        if (wk == 0) {
#pragma unroll
            for (int d2 = 0; d2 < 2; ++d2)
#pragma unroll
                for (int r = 0; r < 16; ++r)
                    of[halfd * 2 + d2][r] += pO[((wq * 2 + d2) * 16 + r) * 64 + lane];
            if (halfd == 0) {
#pragma unroll
                for (int r = 0; r < 16; ++r)
                    lacc[r] += pL[(wq * 16 + r) * 64 + lane];
            }
        }
        __syncthreads();
    }

    if (wk == 0) {
#pragma unroll
        for (int r = 0; r < 16; ++r) {
            float iv = 1.0f / lacc[r];
            int row = q0 + wq * 32 + (r & 3) + 8 * (r >> 2) + 4 * hf;
#pragma unroll
            for (int dcb = 0; dcb < 4; ++dcb)
                g_q[(size_t)row * DIMC + h * DHD + dcb * 32 + l32] = f2b(of[dcb][r] * iv);
        }
    }
}

extern "C" void kernel_launch(void* const* d_in, const int* in_sizes, int n_in,
                              void* d_out, int out_size, void* d_ws, size_t ws_size,
                              hipStream_t stream) {
    const float* hidden = (const float*)d_in[0];
    const float* fc = (const float*)d_in[1];
    const float* fs = (const float*)d_in[2];
    const float* Wq = (const float*)d_in[3];
    const float* bq = (const float*)d_in[4];
    const float* Wk = (const float*)d_in[5];
    const float* bk = (const float*)d_in[6];
    const float* Wv = (const float*)d_in[7];
    const float* bv = (const float*)d_in[8];
    const float* Wo = (const float*)d_in[9];
    const float* bo = (const float*)d_in[10];
    const float* gq = (const float*)d_in[11];
    const float* gk = (const float*)d_in[12];

    dim3 blk(256);
    conv_h<<<dim3(4096), blk, 0, stream>>>(hidden);
    prep_w<<<dim3(32, 32, 4), blk, 0, stream>>>(Wq, Wk, Wv, Wo);
    gemm_qkv<<<dim3(16, 32, 3), blk, 0, stream>>>(bq, bk, bv);
    rmsnorm_rope<<<dim3(SEQ, 2), blk, 0, stream>>>(gq, gk, fc, fs);
    transpose_v<<<dim3(64, 2, NH), blk, 0, stream>>>();
    attn_k<<<dim3(32, NH), dim3(512), 0, stream>>>();
    gemm_o<<<dim3(16, 32), blk, 0, stream>>>(bo, (float*)d_out);
}

// Round 5
// 539.117 us; speedup vs baseline: 1.3378x; 1.3378x over previous
//
#include <hip/hip_runtime.h>
#include <hip/hip_bf16.h>

#define SEQ 4096
#define DIMC 2048
#define NH 16
#define DHD 128

typedef short s8v __attribute__((ext_vector_type(8)));
typedef float f4v __attribute__((ext_vector_type(4)));
typedef __bf16 bf8 __attribute__((ext_vector_type(8)));
typedef float f4 __attribute__((ext_vector_type(4)));
typedef float f16v __attribute__((ext_vector_type(16)));
typedef int i4v __attribute__((ext_vector_type(4)));

typedef __attribute__((address_space(3))) void lds_t;
typedef __attribute__((address_space(1))) void gbl_t;

// Static device scratch (112 MiB). No d_ws dependence.
__device__ __attribute__((aligned(256))) short g_h[(size_t)SEQ * DIMC];
__device__ __attribute__((aligned(256))) short g_q[(size_t)SEQ * DIMC];
__device__ __attribute__((aligned(256))) short g_k[(size_t)SEQ * DIMC];
__device__ __attribute__((aligned(256))) short g_v[(size_t)SEQ * DIMC];
__device__ __attribute__((aligned(256))) short g_vt[(size_t)DIMC * SEQ];     // [h*128+d][s]
__device__ __attribute__((aligned(256))) short g_wt[4][(size_t)DIMC * DIMC]; // [n][k]

__device__ __forceinline__ float b2f(short s) {
    union { unsigned u; float f; } v;
    v.u = ((unsigned)(unsigned short)s) << 16;
    return v.f;
}
__device__ __forceinline__ short f2b(float f) {
    union { float f; unsigned u; } v;
    v.f = f;
    unsigned b = v.u;
    b += 0x7FFFu + ((b >> 16) & 1u);   // RNE
    return (short)(b >> 16);
}
__device__ __forceinline__ f4 mfma16(bf8 a, bf8 b, f4 c) {
    return __builtin_amdgcn_mfma_f32_16x16x32_bf16(a, b, c, 0, 0, 0);
}
__device__ __forceinline__ f16v mfma32(bf8 a, bf8 b, f16v c) {
    return __builtin_amdgcn_mfma_f32_32x32x16_bf16(a, b, c, 0, 0, 0);
}
__device__ __forceinline__ void gl_lds16(const short* g, short* l) {
    __builtin_amdgcn_global_load_lds((gbl_t*)g, (lds_t*)l, 16, 0, 0);
}
// v_permlane32_swap_b32: a' = [a_lo, b_lo], b' = [a_hi, b_hi] (32-lane halves)
__device__ __forceinline__ void plane32_swap(int& a, int& b) {
    asm volatile("v_permlane32_swap_b32 %0, %1" : "+v"(a), "+v"(b));
}
// packed f32 pair -> one u32 of 2x bf16 (RNE), T12 recipe (no builtin on gfx950)
__device__ __forceinline__ int pk2b(float a, float b) {
    int r;
    asm("v_cvt_pk_bf16_f32 %0, %1, %2" : "=v"(r) : "v"(a), "v"(b));
    return r;
}

// ---------------- hidden f32 -> g_h bf16 ----------------
__global__ __launch_bounds__(256) void conv_h(const float* __restrict__ src) {
    size_t i = ((size_t)blockIdx.x * 256 + threadIdx.x) * 8;
    f4v u0 = *reinterpret_cast<const f4v*>(src + i);
    f4v u1 = *reinterpret_cast<const f4v*>(src + i + 4);
    s8v t;
    for (int j = 0; j < 4; ++j) { t[j] = f2b(u0[j]); t[4 + j] = f2b(u1[j]); }
    *reinterpret_cast<s8v*>(g_h + i) = t;
}

// ---------------- W f32 [k][n] -> g_wt[z] bf16 [n][k] ----------------
// LDS tile with 8-float column blocks rotated by (row>>3): column-gather
// reads go from 8-way bank conflict to 2-way (free); f4v writes stay
// 16B-aligned and conflict-free.
__global__ __launch_bounds__(256) void prep_w(const float* __restrict__ W0,
                                              const float* __restrict__ W1,
                                              const float* __restrict__ W2,
                                              const float* __restrict__ W3) {
    __shared__ __attribute__((aligned(16))) float t[64][64];
    const int z = blockIdx.z;
    const float* W = (z == 0) ? W0 : (z == 1) ? W1 : (z == 2) ? W2 : W3;
    short* WT = g_wt[z];
    const int r0 = blockIdx.y * 64, c0 = blockIdx.x * 64;   // r=k, c=n
    const int tid = threadIdx.x;
    for (int i = 0; i < 4; ++i) {
        int slot = tid + i * 256;
        int r = slot >> 4, c4 = (slot & 15) * 4;
        int pb = ((c4 >> 3) + (r >> 3)) & 7;                // rotated phys block
        *reinterpret_cast<f4v*>(&t[r][pb * 8 + (c4 & 7)]) =
            *reinterpret_cast<const f4v*>(&W[(size_t)(r0 + r) * DIMC + c0 + c4]);
    }
    __syncthreads();
    for (int i = 0; i < 2; ++i) {
        int slot = tid + i * 256;
        int n = slot >> 3, k8 = (slot & 7) * 8;
        int pb = ((n >> 3) + (slot & 7)) & 7;               // row>>3 == slot&7 for all j
        s8v o;
        for (int j = 0; j < 8; ++j) o[j] = f2b(t[k8 + j][pb * 8 + (n & 7)]);
        *reinterpret_cast<s8v*>(&WT[(size_t)(c0 + n) * DIMC + r0 + k8]) = o;
    }
}

// ---------------- shared GEMM body (m97-style: global_load_lds staging) ------
template <int DSTF>
__device__ __forceinline__ void gemm_body(const short* __restrict__ X,
                                          const short* __restrict__ Bw,
                                          const float* __restrict__ bias,
                                          short* __restrict__ Yb,
                                          float* __restrict__ Yf,
                                          int bm, int bn) {
    __shared__ __attribute__((aligned(16))) short As[128 * 32];
    __shared__ __attribute__((aligned(16))) short Bs[128 * 32];
    const int tid = threadIdx.x;
    const int w = tid >> 6, lane = tid & 63;
    const int l16 = lane & 15, quad = lane >> 4;
    const int wm = w & 1, wn = w >> 1;

    f4 acc[4][4];
    for (int mi = 0; mi < 4; ++mi)
        for (int ni = 0; ni < 4; ++ni) acc[mi][ni] = (f4)0.0f;

    const int s0 = tid, s1 = tid + 256;
    const int ra0 = s0 >> 2, ca0 = (s0 & 3) * 8;
    const int ra1 = s1 >> 2, ca1 = (s1 & 3) * 8;
    const size_t xo0 = (size_t)(bm * 128 + ra0) * DIMC + ca0;
    const size_t xo1 = (size_t)(bm * 128 + ra1) * DIMC + ca1;
    const size_t bo0 = (size_t)(bn * 128 + ra0) * DIMC + ca0;
    const size_t bo1 = (size_t)(bn * 128 + ra1) * DIMC + ca1;
    short* lda0 = As + (size_t)(0 * 256 + w * 64) * 8;
    short* lda1 = As + (size_t)(1 * 256 + w * 64) * 8;
    short* ldb0 = Bs + (size_t)(0 * 256 + w * 64) * 8;
    short* ldb1 = Bs + (size_t)(1 * 256 + w * 64) * 8;

    for (int kb = 0; kb < DIMC; kb += 32) {
        __syncthreads();
        gl_lds16(X + xo0 + kb, lda0);
        gl_lds16(X + xo1 + kb, lda1);
        gl_lds16(Bw + bo0 + kb, ldb0);
        gl_lds16(Bw + bo1 + kb, ldb1);
        __syncthreads();
        bf8 af[4], bfr[4];
        for (int mi = 0; mi < 4; ++mi)
            af[mi] = *reinterpret_cast<const bf8*>(As + (wm * 64 + mi * 16 + l16) * 32 + quad * 8);
        for (int ni = 0; ni < 4; ++ni)
            bfr[ni] = *reinterpret_cast<const bf8*>(Bs + (wn * 64 + ni * 16 + l16) * 32 + quad * 8);
        for (int mi = 0; mi < 4; ++mi)
            for (int ni = 0; ni < 4; ++ni)
                acc[mi][ni] = mfma16(af[mi], bfr[ni], acc[mi][ni]);
    }

    for (int ni = 0; ni < 4; ++ni) {
        int col = bn * 128 + wn * 64 + ni * 16 + l16;
        float bcol = bias[col];
        for (int mi = 0; mi < 4; ++mi) {
            int row = bm * 128 + wm * 64 + mi * 16 + quad * 4;
            for (int r = 0; r < 4; ++r) {
                if (DSTF)
                    Yf[(size_t)(row + r) * DIMC + col] = acc[mi][ni][r] + bcol;
                else
                    Yb[(size_t)(row + r) * DIMC + col] = f2b(acc[mi][ni][r] + bcol);
            }
        }
    }
}

__global__ __launch_bounds__(256, 2) void gemm_qkv(const float* __restrict__ bq,
                                                   const float* __restrict__ bk,
                                                   const float* __restrict__ bv) {
    const int z = blockIdx.z;
    const float* bias = (z == 0) ? bq : (z == 1) ? bk : bv;
    short* Y = (z == 0) ? g_q : (z == 1) ? g_k : g_v;
    gemm_body<0>(g_h, g_wt[z], bias, Y, nullptr, blockIdx.y, blockIdx.x);
}

__global__ __launch_bounds__(256, 2) void gemm_o(const float* __restrict__ bias,
                                                 float* __restrict__ Yf) {
    gemm_body<1>(g_q, g_wt[3], bias, nullptr, Yf, blockIdx.y, blockIdx.x);
}

// ---------------- fused RMSNorm + RoPE, in place on g_q/g_k ------
// q pre-scaled by log2(e)/sqrt(DHD) (folded attn scale + exp2 conversion).
// Single __syncthreads: every thread sums the 4 wave partials itself.
__global__ __launch_bounds__(256) void rmsnorm_rope(const float* __restrict__ gq,
                                                    const float* __restrict__ gk,
                                                    const float* __restrict__ fc,
                                                    const float* __restrict__ fs) {
    __shared__ float partial[4];
    const int s = blockIdx.x;
    const int which = blockIdx.y;
    short* x = which ? g_k : g_q;
    const float* g = which ? gk : gq;
    const int tid = threadIdx.x;
    const int d0 = tid * 8;

    s8v xv = *reinterpret_cast<const s8v*>(&x[(size_t)s * DIMC + d0]);
    float xf[8];
    float ssq = 0.0f;
    for (int j = 0; j < 8; ++j) { xf[j] = b2f(xv[j]); ssq += xf[j] * xf[j]; }
    for (int off = 32; off; off >>= 1) ssq += __shfl_down(ssq, off);
    if ((tid & 63) == 0) partial[tid >> 6] = ssq;
    __syncthreads();
    float tot = partial[0] + partial[1] + partial[2] + partial[3];
    float rs = rsqrtf(tot * (1.0f / (float)DIMC) + 1e-5f);
    if (which == 0) rs *= 0.12751744f;   // log2(e)/sqrt(128)

    f4v g0 = *reinterpret_cast<const f4v*>(&g[d0]);
    f4v g1 = *reinterpret_cast<const f4v*>(&g[d0 + 4]);
    float xn[8];
    for (int j = 0; j < 4; ++j) { xn[j] = xf[j] * rs * g0[j]; xn[4 + j] = xf[4 + j] * rs * g1[j]; }

    s8v ov;
    for (int p = 0; p < 4; ++p) {
        int e = d0 + 2 * p;
        int hd = e & (DHD - 1);
        float c = fc[(size_t)s * DHD + hd];
        float sn = fs[(size_t)s * DHD + hd + 1];
        float x1 = xn[2 * p], x2 = xn[2 * p + 1];
        ov[2 * p]     = f2b(x1 * c - x2 * sn);
        ov[2 * p + 1] = f2b(x1 * sn + x2 * c);
    }
    *reinterpret_cast<s8v*>(&x[(size_t)s * DIMC + d0]) = ov;
}

// ---------------- V transpose: g_v [s][h*128+d] -> g_vt [h*128+d][s] ---------
// LDS tile with 8-short column blocks rotated by (row>>3): the column-gather
// reads become conflict-free (were 8-way); s8v writes keep 16B alignment.
__global__ __launch_bounds__(256) void transpose_v() {
    __shared__ __attribute__((aligned(16))) short t[64][64];
    const int h = blockIdx.z, dt = blockIdx.y, st = blockIdx.x;
    const int tid = threadIdx.x;
    const short* src = g_v + (size_t)st * 64 * DIMC + h * DHD + dt * 64;
    for (int i = 0; i < 2; ++i) {
        int slot = tid + i * 256;
        int s = slot >> 3, db = slot & 7;
        int pb = (db + (s >> 3)) & 7;                       // rotated phys block
        *reinterpret_cast<s8v*>(&t[s][pb * 8]) =
            *reinterpret_cast<const s8v*>(src + (size_t)s * DIMC + db * 8);
    }
    __syncthreads();
    short* dst = g_vt + (size_t)(h * DHD + dt * 64) * SEQ + st * 64;
    for (int i = 0; i < 2; ++i) {
        int slot = tid + i * 256;
        int d = slot >> 3, sb = (slot & 7) * 8;
        int pb = ((d >> 3) + (slot & 7)) & 7;               // row>>3 == slot&7 for all j
        s8v o;
        for (int j = 0; j < 8; ++j) o[j] = t[sb + j][pb * 8 + (d & 7)];
        *reinterpret_cast<s8v*>(dst + (size_t)d * SEQ + sb) = o;
    }
}

// ---------------- flash attention, 32x32 MFMA, in-register softmax (T12) -----
// (verified round-3 version: 184 us, MfmaUtil 39, VALU 46, 2 blk/CU)
// Swapped QK^T: sa = mfma32(K, Q) -> D[key][q], q = lane&31. P converted to
// bf16 pairs (v_cvt_pk_bf16_f32) and redistributed to the PV A-frag layout
// with v_permlane32_swap — no LDS round-trip in the softmax. Row-sum l via
// ones-MFMA. K/V double-buffered via async global_load_lds (rotated column
// blocks) with counted vmcnt.
__global__ __launch_bounds__(256, 2) void attn_k() {
    __shared__ __attribute__((aligned(16))) short Ks0[2][64 * 128];   // [buf][key][dh], cb rotated by key
    __shared__ __attribute__((aligned(16))) short Vt0[2][128 * 64];   // [buf][dh][key], kb rotated by dh

    const int h = blockIdx.y;
    const int q0 = blockIdx.x * 128;
    const int tid = threadIdx.x;
    const int w = tid >> 6, lane = tid & 63;
    const int l32 = lane & 31, hf = lane >> 5;
    const int l16 = lane & 15;
    const int cbase = hf + l16;        // K read: cs = (dc*2 + cbase) & 15
    const int khl = hf + l32;          // V read: ks = (kc*4 + kp*2 + khl) & 7

    // Q B-frags: qf[dc] = Q[q = q0+w*32+l32][d = dc*16 + hf*8 .. +7]
    bf8 qf[8];
    {
        const short* qb = g_q + (size_t)(q0 + w * 32 + l32) * DIMC + h * DHD + hf * 8;
#pragma unroll
        for (int dc = 0; dc < 8; ++dc)
            qf[dc] = *reinterpret_cast<const bf8*>(qb + dc * 16);
    }

    f16v of[4];
#pragma unroll
    for (int i = 0; i < 4; ++i) of[i] = (f16v)0.0f;
    f16v lacc = (f16v)0.0f;
    const f16v fz = (f16v)0.0f;

    s8v ob;
#pragma unroll
    for (int j = 0; j < 8; ++j) ob[j] = (short)0x3F80;   // bf16 1.0
    const bf8 vones = __builtin_bit_cast(bf8, ob);

    const short* Kbase = g_k + h * DHD;
    const short* Vbase = g_vt + (size_t)h * DHD * SEQ;

    const short* kp[4];
    const short* vp[4];
#pragma unroll
    for (int i = 0; i < 4; ++i) {
        int s = tid + i * 256;
        int krow = s >> 4, kcb = ((s & 15) - krow) & 15;   // rotated global cb
        int vd = s >> 3, vkb = ((s & 7) - vd) & 7;         // rotated global kb
        kp[i] = Kbase + (size_t)krow * DIMC + kcb * 8;
        vp[i] = Vbase + (size_t)vd * SEQ + vkb * 8;
    }

    // prologue: stage tile 0 into buffer 0 (8 loads in flight)
#pragma unroll
    for (int i = 0; i < 4; ++i) {
        gl_lds16(kp[i], &Ks0[0][(size_t)(i * 256 + w * 64) * 8]);
        kp[i] += (size_t)64 * DIMC;
    }
#pragma unroll
    for (int i = 0; i < 4; ++i) {
        gl_lds16(vp[i], &Vt0[0][(size_t)(i * 256 + w * 64) * 8]);
        vp[i] += 64;
    }

    for (int kt = 0; kt < SEQ; kt += 64) {
        const int cur = (kt >> 6) & 1;
        // stage tile t+1 into the other buffer, then wait ONLY tile t's 8 loads
        if (kt + 64 < SEQ) {
            const int nxt = cur ^ 1;
#pragma unroll
            for (int i = 0; i < 4; ++i) {
                gl_lds16(kp[i], &Ks0[nxt][(size_t)(i * 256 + w * 64) * 8]);
                kp[i] += (size_t)64 * DIMC;
            }
#pragma unroll
            for (int i = 0; i < 4; ++i) {
                gl_lds16(vp[i], &Vt0[nxt][(size_t)(i * 256 + w * 64) * 8]);
                vp[i] += 64;
            }
            asm volatile("s_waitcnt vmcnt(8)" ::: "memory");
        } else {
            asm volatile("s_waitcnt vmcnt(0)" ::: "memory");
        }
        __builtin_amdgcn_sched_barrier(0);
        __builtin_amdgcn_s_barrier();   // all waves' tile-t loads landed
        __builtin_amdgcn_sched_barrier(0);

        const short* Ks = Ks0[cur];
        const short* Vt = Vt0[cur];

#pragma unroll
        for (int kc = 0; kc < 2; ++kc) {
            // ---- swapped QK^T: sa = K.Q^T -> D[key = kc*32+rowmap][q = l32]
            const short* krb = Ks + (kc * 32 + l32) * 128;
            __builtin_amdgcn_s_setprio(1);
            f16v sa = mfma32(*reinterpret_cast<const bf8*>(krb + ((cbase & 15) << 3)), qf[0], fz);
#pragma unroll
            for (int dc = 1; dc < 8; ++dc) {
                bf8 kf = *reinterpret_cast<const bf8*>(krb + (((dc * 2 + cbase) & 15) << 3));
                sa = mfma32(kf, qf[dc], sa);
            }
            __builtin_amdgcn_s_setprio(0);

            // ---- p = exp2(s), pack pairs to bf16 words
            // reg->key: key = kc*32 + (r&3) + 8*(r>>2) + 4*hf;  wv[t]=pk(e[2t],e[2t+1])
            int wv[8];
#pragma unroll
            for (int t = 0; t < 8; ++t) {
                float e0 = exp2f(sa[2 * t]);
                float e1 = exp2f(sa[2 * t + 1]);
                wv[t] = pk2b(e0, e1);
            }
            // ---- cross-half redistribution -> PV A-frags (16 keys each)
            int a0 = wv[0], b0 = wv[2]; plane32_swap(a0, b0);
            int a1 = wv[1], b1 = wv[3]; plane32_swap(a1, b1);
            int a2 = wv[4], b2 = wv[6]; plane32_swap(a2, b2);
            int a3 = wv[5], b3 = wv[7]; plane32_swap(a3, b3);
            i4v pw0 = {a0, a1, b0, b1};
            i4v pw1 = {a2, a3, b2, b3};
            bf8 pa0 = __builtin_bit_cast(bf8, pw0);
            bf8 pa1 = __builtin_bit_cast(bf8, pw1);

            __builtin_amdgcn_s_setprio(1);
            // ---- l += P . 1 (rows align with of)
            lacc = mfma32(pa0, vones, lacc);
            lacc = mfma32(pa1, vones, lacc);

            // ---- P V: of[dcb] over d = dcb*32 + l32; keys chunk kc*2+kp
#pragma unroll
            for (int kp2 = 0; kp2 < 2; ++kp2) {
                bf8 pa = kp2 ? pa1 : pa0;
#pragma unroll
                for (int dcb = 0; dcb < 4; ++dcb) {
                    int d = dcb * 32 + l32;
                    int ks = (kc * 4 + kp2 * 2 + khl) & 7;
                    bf8 vf = *reinterpret_cast<const bf8*>(Vt + d * 64 + ks * 8);
                    of[dcb] = mfma32(pa, vf, of[dcb]);
                }
            }
            __builtin_amdgcn_s_setprio(0);
        }

        __builtin_amdgcn_s_barrier();   // all reads of buf[cur] done before re-stage
        __builtin_amdgcn_sched_barrier(0);
    }

    // epilogue: normalize and write back to g_q
#pragma unroll
    for (int r = 0; r < 16; ++r) {
        float iv = 1.0f / lacc[r];
        int row = q0 + w * 32 + (r & 3) + 8 * (r >> 2) + 4 * hf;
#pragma unroll
        for (int dcb = 0; dcb < 4; ++dcb)
            g_q[(size_t)row * DIMC + h * DHD + dcb * 32 + l32] = f2b(of[dcb][r] * iv);
    }
}

extern "C" void kernel_launch(void* const* d_in, const int* in_sizes, int n_in,
                              void* d_out, int out_size, void* d_ws, size_t ws_size,
                              hipStream_t stream) {
    const float* hidden = (const float*)d_in[0];
    const float* fc = (const float*)d_in[1];
    const float* fs = (const float*)d_in[2];
    const float* Wq = (const float*)d_in[3];
    const float* bq = (const float*)d_in[4];
    const float* Wk = (const float*)d_in[5];
    const float* bk = (const float*)d_in[6];
    const float* Wv = (const float*)d_in[7];
    const float* bv = (const float*)d_in[8];
    const float* Wo = (const float*)d_in[9];
    const float* bo = (const float*)d_in[10];
    const float* gq = (const float*)d_in[11];
    const float* gk = (const float*)d_in[12];

    dim3 blk(256);
    conv_h<<<dim3(4096), blk, 0, stream>>>(hidden);
    prep_w<<<dim3(32, 32, 4), blk, 0, stream>>>(Wq, Wk, Wv, Wo);
    gemm_qkv<<<dim3(16, 32, 3), blk, 0, stream>>>(bq, bk, bv);
    rmsnorm_rope<<<dim3(SEQ, 2), blk, 0, stream>>>(gq, gk, fc, fs);
    transpose_v<<<dim3(64, 2, NH), blk, 0, stream>>>();
    attn_k<<<dim3(32, NH), blk, 0, stream>>>();
    gemm_o<<<dim3(16, 32), blk, 0, stream>>>(bo, (float*)d_out);
}

// Round 6
// 515.551 us; speedup vs baseline: 1.3989x; 1.0457x over previous
//
#include <hip/hip_runtime.h>
#include <hip/hip_bf16.h>

#define SEQ 4096
#define DIMC 2048
#define NH 16
#define DHD 128

typedef short s8v __attribute__((ext_vector_type(8)));
typedef float f4v __attribute__((ext_vector_type(4)));
typedef __bf16 bf8 __attribute__((ext_vector_type(8)));
typedef float f4 __attribute__((ext_vector_type(4)));
typedef float f16v __attribute__((ext_vector_type(16)));
typedef int i4v __attribute__((ext_vector_type(4)));

typedef __attribute__((address_space(3))) void lds_t;
typedef __attribute__((address_space(1))) void gbl_t;

// Static device scratch (112 MiB). No d_ws dependence.
__device__ __attribute__((aligned(256))) short g_h[(size_t)SEQ * DIMC];
__device__ __attribute__((aligned(256))) short g_q[(size_t)SEQ * DIMC];
__device__ __attribute__((aligned(256))) short g_k[(size_t)SEQ * DIMC];
__device__ __attribute__((aligned(256))) short g_v[(size_t)SEQ * DIMC];
__device__ __attribute__((aligned(256))) short g_vt[(size_t)DIMC * SEQ];     // [h*128+d][s]
__device__ __attribute__((aligned(256))) short g_wt[4][(size_t)DIMC * DIMC]; // [n][k]

__device__ __forceinline__ float b2f(short s) {
    union { unsigned u; float f; } v;
    v.u = ((unsigned)(unsigned short)s) << 16;
    return v.f;
}
__device__ __forceinline__ short f2b(float f) {
    union { float f; unsigned u; } v;
    v.f = f;
    unsigned b = v.u;
    b += 0x7FFFu + ((b >> 16) & 1u);   // RNE
    return (short)(b >> 16);
}
__device__ __forceinline__ f4 mfma16(bf8 a, bf8 b, f4 c) {
    return __builtin_amdgcn_mfma_f32_16x16x32_bf16(a, b, c, 0, 0, 0);
}
__device__ __forceinline__ f16v mfma32(bf8 a, bf8 b, f16v c) {
    return __builtin_amdgcn_mfma_f32_32x32x16_bf16(a, b, c, 0, 0, 0);
}
__device__ __forceinline__ void gl_lds16(const short* g, short* l) {
    __builtin_amdgcn_global_load_lds((gbl_t*)g, (lds_t*)l, 16, 0, 0);
}
// v_permlane32_swap_b32: a' = [a_lo, b_lo], b' = [a_hi, b_hi] (32-lane halves)
// non-volatile: pure register transform, keep it schedulable
__device__ __forceinline__ void plane32_swap(int& a, int& b) {
    asm("v_permlane32_swap_b32 %0, %1" : "+v"(a), "+v"(b));
}
// packed f32 pair -> one u32 of 2x bf16 (RNE), T12 recipe (no builtin on gfx950)
__device__ __forceinline__ int pk2b(float a, float b) {
    int r;
    asm("v_cvt_pk_bf16_f32 %0, %1, %2" : "=v"(r) : "v"(a), "v"(b));
    return r;
}
// raw v_exp_f32 (2^x) — skips OCML denormal fixup; inputs here are far from
// the subnormal boundary and output is rounded to bf16 anyway.
__device__ __forceinline__ float fexp2(float x) {
#if __has_builtin(__builtin_amdgcn_exp2f)
    return __builtin_amdgcn_exp2f(x);
#else
    float r;
    asm("v_exp_f32 %0, %1" : "=v"(r) : "v"(x));
    return r;
#endif
}

// ---------------- hidden f32 -> g_h bf16 ----------------
__global__ __launch_bounds__(256) void conv_h(const float* __restrict__ src) {
    size_t i = ((size_t)blockIdx.x * 256 + threadIdx.x) * 8;
    f4v u0 = *reinterpret_cast<const f4v*>(src + i);
    f4v u1 = *reinterpret_cast<const f4v*>(src + i + 4);
    s8v t;
    for (int j = 0; j < 4; ++j) { t[j] = f2b(u0[j]); t[4 + j] = f2b(u1[j]); }
    *reinterpret_cast<s8v*>(g_h + i) = t;
}

// ---------------- W f32 [k][n] -> g_wt[z] bf16 [n][k] ----------------
__global__ __launch_bounds__(256) void prep_w(const float* __restrict__ W0,
                                              const float* __restrict__ W1,
                                              const float* __restrict__ W2,
                                              const float* __restrict__ W3) {
    __shared__ __attribute__((aligned(16))) float t[64][64];
    const int z = blockIdx.z;
    const float* W = (z == 0) ? W0 : (z == 1) ? W1 : (z == 2) ? W2 : W3;
    short* WT = g_wt[z];
    const int r0 = blockIdx.y * 64, c0 = blockIdx.x * 64;   // r=k, c=n
    const int tid = threadIdx.x;
    for (int i = 0; i < 4; ++i) {
        int slot = tid + i * 256;
        int r = slot >> 4, c4 = (slot & 15) * 4;
        int pb = ((c4 >> 3) + (r >> 3)) & 7;                // rotated phys block
        *reinterpret_cast<f4v*>(&t[r][pb * 8 + (c4 & 7)]) =
            *reinterpret_cast<const f4v*>(&W[(size_t)(r0 + r) * DIMC + c0 + c4]);
    }
    __syncthreads();
    for (int i = 0; i < 2; ++i) {
        int slot = tid + i * 256;
        int n = slot >> 3, k8 = (slot & 7) * 8;
        int pb = ((n >> 3) + (slot & 7)) & 7;               // row>>3 == slot&7 for all j
        s8v o;
        for (int j = 0; j < 8; ++j) o[j] = f2b(t[k8 + j][pb * 8 + (n & 7)]);
        *reinterpret_cast<s8v*>(&WT[(size_t)(c0 + n) * DIMC + r0 + k8]) = o;
    }
}

// ---------------- shared GEMM body (m97-style: global_load_lds staging) ------
template <int DSTF>
__device__ __forceinline__ void gemm_body(const short* __restrict__ X,
                                          const short* __restrict__ Bw,
                                          const float* __restrict__ bias,
                                          short* __restrict__ Yb,
                                          float* __restrict__ Yf,
                                          int bm, int bn) {
    __shared__ __attribute__((aligned(16))) short As[128 * 32];
    __shared__ __attribute__((aligned(16))) short Bs[128 * 32];
    const int tid = threadIdx.x;
    const int w = tid >> 6, lane = tid & 63;
    const int l16 = lane & 15, quad = lane >> 4;
    const int wm = w & 1, wn = w >> 1;

    f4 acc[4][4];
    for (int mi = 0; mi < 4; ++mi)
        for (int ni = 0; ni < 4; ++ni) acc[mi][ni] = (f4)0.0f;

    const int s0 = tid, s1 = tid + 256;
    const int ra0 = s0 >> 2, ca0 = (s0 & 3) * 8;
    const int ra1 = s1 >> 2, ca1 = (s1 & 3) * 8;
    const size_t xo0 = (size_t)(bm * 128 + ra0) * DIMC + ca0;
    const size_t xo1 = (size_t)(bm * 128 + ra1) * DIMC + ca1;
    const size_t bo0 = (size_t)(bn * 128 + ra0) * DIMC + ca0;
    const size_t bo1 = (size_t)(bn * 128 + ra1) * DIMC + ca1;
    short* lda0 = As + (size_t)(0 * 256 + w * 64) * 8;
    short* lda1 = As + (size_t)(1 * 256 + w * 64) * 8;
    short* ldb0 = Bs + (size_t)(0 * 256 + w * 64) * 8;
    short* ldb1 = Bs + (size_t)(1 * 256 + w * 64) * 8;

    for (int kb = 0; kb < DIMC; kb += 32) {
        __syncthreads();
        gl_lds16(X + xo0 + kb, lda0);
        gl_lds16(X + xo1 + kb, lda1);
        gl_lds16(Bw + bo0 + kb, ldb0);
        gl_lds16(Bw + bo1 + kb, ldb1);
        __syncthreads();
        bf8 af[4], bfr[4];
        for (int mi = 0; mi < 4; ++mi)
            af[mi] = *reinterpret_cast<const bf8*>(As + (wm * 64 + mi * 16 + l16) * 32 + quad * 8);
        for (int ni = 0; ni < 4; ++ni)
            bfr[ni] = *reinterpret_cast<const bf8*>(Bs + (wn * 64 + ni * 16 + l16) * 32 + quad * 8);
        for (int mi = 0; mi < 4; ++mi)
            for (int ni = 0; ni < 4; ++ni)
                acc[mi][ni] = mfma16(af[mi], bfr[ni], acc[mi][ni]);
    }

    for (int ni = 0; ni < 4; ++ni) {
        int col = bn * 128 + wn * 64 + ni * 16 + l16;
        float bcol = bias[col];
        for (int mi = 0; mi < 4; ++mi) {
            int row = bm * 128 + wm * 64 + mi * 16 + quad * 4;
            for (int r = 0; r < 4; ++r) {
                if (DSTF)
                    Yf[(size_t)(row + r) * DIMC + col] = acc[mi][ni][r] + bcol;
                else
                    Yb[(size_t)(row + r) * DIMC + col] = f2b(acc[mi][ni][r] + bcol);
            }
        }
    }
}

__global__ __launch_bounds__(256, 2) void gemm_qkv(const float* __restrict__ bq,
                                                   const float* __restrict__ bk,
                                                   const float* __restrict__ bv) {
    const int z = blockIdx.z;
    const float* bias = (z == 0) ? bq : (z == 1) ? bk : bv;
    short* Y = (z == 0) ? g_q : (z == 1) ? g_k : g_v;
    gemm_body<0>(g_h, g_wt[z], bias, Y, nullptr, blockIdx.y, blockIdx.x);
}

__global__ __launch_bounds__(256, 2) void gemm_o(const float* __restrict__ bias,
                                                 float* __restrict__ Yf) {
    gemm_body<1>(g_q, g_wt[3], bias, nullptr, Yf, blockIdx.y, blockIdx.x);
}

// ---------------- fused RMSNorm + RoPE, in place on g_q/g_k ------
// q pre-scaled by log2(e)/sqrt(DHD) (folded attn scale + exp2 conversion).
__global__ __launch_bounds__(256) void rmsnorm_rope(const float* __restrict__ gq,
                                                    const float* __restrict__ gk,
                                                    const float* __restrict__ fc,
                                                    const float* __restrict__ fs) {
    __shared__ float partial[4];
    const int s = blockIdx.x;
    const int which = blockIdx.y;
    short* x = which ? g_k : g_q;
    const float* g = which ? gk : gq;
    const int tid = threadIdx.x;
    const int d0 = tid * 8;

    s8v xv = *reinterpret_cast<const s8v*>(&x[(size_t)s * DIMC + d0]);
    float xf[8];
    float ssq = 0.0f;
    for (int j = 0; j < 8; ++j) { xf[j] = b2f(xv[j]); ssq += xf[j] * xf[j]; }
    for (int off = 32; off; off >>= 1) ssq += __shfl_down(ssq, off);
    if ((tid & 63) == 0) partial[tid >> 6] = ssq;
    __syncthreads();
    float tot = partial[0] + partial[1] + partial[2] + partial[3];
    float rs = rsqrtf(tot * (1.0f / (float)DIMC) + 1e-5f);
    if (which == 0) rs *= 0.12751744f;   // log2(e)/sqrt(128)

    f4v g0 = *reinterpret_cast<const f4v*>(&g[d0]);
    f4v g1 = *reinterpret_cast<const f4v*>(&g[d0 + 4]);
    float xn[8];
    for (int j = 0; j < 4; ++j) { xn[j] = xf[j] * rs * g0[j]; xn[4 + j] = xf[4 + j] * rs * g1[j]; }

    s8v ov;
    for (int p = 0; p < 4; ++p) {
        int e = d0 + 2 * p;
        int hd = e & (DHD - 1);
        float c = fc[(size_t)s * DHD + hd];
        float sn = fs[(size_t)s * DHD + hd + 1];
        float x1 = xn[2 * p], x2 = xn[2 * p + 1];
        ov[2 * p]     = f2b(x1 * c - x2 * sn);
        ov[2 * p + 1] = f2b(x1 * sn + x2 * c);
    }
    *reinterpret_cast<s8v*>(&x[(size_t)s * DIMC + d0]) = ov;
}

// ---------------- V transpose: g_v [s][h*128+d] -> g_vt [h*128+d][s] ---------
__global__ __launch_bounds__(256) void transpose_v() {
    __shared__ __attribute__((aligned(16))) short t[64][64];
    const int h = blockIdx.z, dt = blockIdx.y, st = blockIdx.x;
    const int tid = threadIdx.x;
    const short* src = g_v + (size_t)st * 64 * DIMC + h * DHD + dt * 64;
    for (int i = 0; i < 2; ++i) {
        int slot = tid + i * 256;
        int s = slot >> 3, db = slot & 7;
        int pb = (db + (s >> 3)) & 7;                       // rotated phys block
        *reinterpret_cast<s8v*>(&t[s][pb * 8]) =
            *reinterpret_cast<const s8v*>(src + (size_t)s * DIMC + db * 8);
    }
    __syncthreads();
    short* dst = g_vt + (size_t)(h * DHD + dt * 64) * SEQ + st * 64;
    for (int i = 0; i < 2; ++i) {
        int slot = tid + i * 256;
        int d = slot >> 3, sb = (slot & 7) * 8;
        int pb = ((d >> 3) + (slot & 7)) & 7;               // row>>3 == slot&7 for all j
        s8v o;
        for (int j = 0; j < 8; ++j) o[j] = t[sb + j][pb * 8 + (d & 7)];
        *reinterpret_cast<s8v*>(dst + (size_t)d * SEQ + sb) = o;
    }
}

// ---------------- flash attention, 32x32 MFMA, in-register softmax (T12) -----
// Dual-chain ILP version: both 32-key halves' QK^T chains computed with
// independent accumulators (interleaved, dep-distance 2 on the MFMA pipe);
// softmax of half 0 overlaps half 1's MFMA tail, softmax of half 1 overlaps
// PV of half 0. No setprio / sched fences inside the compute region — one
// open scheduling region per tile so the compiler can interleave VALU and
// MFMA streams (2 waves/SIMD is LDS-capped; ILP is the only concurrency
// left, r4 showed more waves spill). exp2 via raw v_exp_f32.
__global__ __launch_bounds__(256, 2) void attn_k() {
    __shared__ __attribute__((aligned(16))) short Ks0[2][64 * 128];   // [buf][key][dh], cb rotated by key
    __shared__ __attribute__((aligned(16))) short Vt0[2][128 * 64];   // [buf][dh][key], kb rotated by dh

    const int h = blockIdx.y;
    const int q0 = blockIdx.x * 128;
    const int tid = threadIdx.x;
    const int w = tid >> 6, lane = tid & 63;
    const int l32 = lane & 31, hf = lane >> 5;
    const int l16 = lane & 15;
    const int cbase = hf + l16;        // K read: cs = (dc*2 + cbase) & 15
    const int khl = hf + l32;          // V read: ks = (kc*4 + kp2*2 + khl) & 7

    // Q B-frags: qf[dc] = Q[q = q0+w*32+l32][d = dc*16 + hf*8 .. +7]
    bf8 qf[8];
    {
        const short* qb = g_q + (size_t)(q0 + w * 32 + l32) * DIMC + h * DHD + hf * 8;
#pragma unroll
        for (int dc = 0; dc < 8; ++dc)
            qf[dc] = *reinterpret_cast<const bf8*>(qb + dc * 16);
    }

    f16v of[4];
#pragma unroll
    for (int i = 0; i < 4; ++i) of[i] = (f16v)0.0f;
    f16v lacc = (f16v)0.0f;
    const f16v fz = (f16v)0.0f;

    s8v ob;
#pragma unroll
    for (int j = 0; j < 8; ++j) ob[j] = (short)0x3F80;   // bf16 1.0
    const bf8 vones = __builtin_bit_cast(bf8, ob);

    const short* Kbase = g_k + h * DHD;
    const short* Vbase = g_vt + (size_t)h * DHD * SEQ;

    const short* kp[4];
    const short* vp[4];
#pragma unroll
    for (int i = 0; i < 4; ++i) {
        int s = tid + i * 256;
        int krow = s >> 4, kcb = ((s & 15) - krow) & 15;   // rotated global cb
        int vd = s >> 3, vkb = ((s & 7) - vd) & 7;         // rotated global kb
        kp[i] = Kbase + (size_t)krow * DIMC + kcb * 8;
        vp[i] = Vbase + (size_t)vd * SEQ + vkb * 8;
    }

    // prologue: stage tile 0 into buffer 0 (8 loads in flight)
#pragma unroll
    for (int i = 0; i < 4; ++i) {
        gl_lds16(kp[i], &Ks0[0][(size_t)(i * 256 + w * 64) * 8]);
        kp[i] += (size_t)64 * DIMC;
    }
#pragma unroll
    for (int i = 0; i < 4; ++i) {
        gl_lds16(vp[i], &Vt0[0][(size_t)(i * 256 + w * 64) * 8]);
        vp[i] += 64;
    }

    // in-register softmax: p = exp2(s) packed to bf16, redistributed across
    // 32-lane halves into PV A-frag layout (one permlane32_swap fills TWO words)
    auto softmax_pack = [&](const f16v& sa, bf8& paA, bf8& paB) {
        int wv[8];
#pragma unroll
        for (int t = 0; t < 8; ++t)
            wv[t] = pk2b(fexp2(sa[2 * t]), fexp2(sa[2 * t + 1]));
        int a0 = wv[0], b0 = wv[2]; plane32_swap(a0, b0);
        int a1 = wv[1], b1 = wv[3]; plane32_swap(a1, b1);
        int a2 = wv[4], b2 = wv[6]; plane32_swap(a2, b2);
        int a3 = wv[5], b3 = wv[7]; plane32_swap(a3, b3);
        i4v p0 = {a0, a1, b0, b1};
        i4v p1 = {a2, a3, b2, b3};
        paA = __builtin_bit_cast(bf8, p0);
        paB = __builtin_bit_cast(bf8, p1);
    };

    for (int kt = 0; kt < SEQ; kt += 64) {
        const int cur = (kt >> 6) & 1;
        // stage tile t+1 into the other buffer, then wait ONLY tile t's 8 loads
        if (kt + 64 < SEQ) {
            const int nxt = cur ^ 1;
#pragma unroll
            for (int i = 0; i < 4; ++i) {
                gl_lds16(kp[i], &Ks0[nxt][(size_t)(i * 256 + w * 64) * 8]);
                kp[i] += (size_t)64 * DIMC;
            }
#pragma unroll
            for (int i = 0; i < 4; ++i) {
                gl_lds16(vp[i], &Vt0[nxt][(size_t)(i * 256 + w * 64) * 8]);
                vp[i] += 64;
            }
            asm volatile("s_waitcnt vmcnt(8)" ::: "memory");
        } else {
            asm volatile("s_waitcnt vmcnt(0)" ::: "memory");
        }
        __builtin_amdgcn_sched_barrier(0);
        __builtin_amdgcn_s_barrier();   // all waves' tile-t loads landed
        __builtin_amdgcn_sched_barrier(0);

        const short* Ks = Ks0[cur];
        const short* Vt = Vt0[cur];

        // ---- dual swapped QK^T: sa0/sa1 = K.Q^T for key halves 0/1
        const short* krb0 = Ks + l32 * 128;
        const short* krb1 = Ks + (32 + l32) * 128;
        f16v sa0, sa1;
        {
            bf8 k0 = *reinterpret_cast<const bf8*>(krb0 + ((cbase & 15) << 3));
            bf8 k1 = *reinterpret_cast<const bf8*>(krb1 + ((cbase & 15) << 3));
            sa0 = mfma32(k0, qf[0], fz);
            sa1 = mfma32(k1, qf[0], fz);
        }
#pragma unroll
        for (int dc = 1; dc < 8; ++dc) {
            const int cs = ((dc * 2 + cbase) & 15) << 3;
            bf8 k0 = *reinterpret_cast<const bf8*>(krb0 + cs);
            sa0 = mfma32(k0, qf[dc], sa0);
            bf8 k1 = *reinterpret_cast<const bf8*>(krb1 + cs);
            sa1 = mfma32(k1, qf[dc], sa1);
        }

        // ---- half 0: softmax (overlaps sa1's MFMA tail) + lacc + PV
        bf8 p00, p01;
        softmax_pack(sa0, p00, p01);
        lacc = mfma32(p00, vones, lacc);
        lacc = mfma32(p01, vones, lacc);
#pragma unroll
        for (int kp2 = 0; kp2 < 2; ++kp2) {
            bf8 pa = kp2 ? p01 : p00;
#pragma unroll
            for (int dcb = 0; dcb < 4; ++dcb) {
                bf8 vf = *reinterpret_cast<const bf8*>(
                    Vt + (dcb * 32 + l32) * 64 + (((kp2 * 2 + khl) & 7) << 3));
                of[dcb] = mfma32(pa, vf, of[dcb]);
            }
        }

        // ---- half 1: softmax (overlaps PV0's MFMAs) + lacc + PV
        bf8 p10, p11;
        softmax_pack(sa1, p10, p11);
        lacc = mfma32(p10, vones, lacc);
        lacc = mfma32(p11, vones, lacc);
#pragma unroll
        for (int kp2 = 0; kp2 < 2; ++kp2) {
            bf8 pa = kp2 ? p11 : p10;
#pragma unroll
            for (int dcb = 0; dcb < 4; ++dcb) {
                bf8 vf = *reinterpret_cast<const bf8*>(
                    Vt + (dcb * 32 + l32) * 64 + (((4 + kp2 * 2 + khl) & 7) << 3));
                of[dcb] = mfma32(pa, vf, of[dcb]);
            }
        }

        __builtin_amdgcn_s_barrier();   // all reads of buf[cur] done before re-stage
        __builtin_amdgcn_sched_barrier(0);
    }

    // epilogue: normalize and write back to g_q
#pragma unroll
    for (int r = 0; r < 16; ++r) {
        float iv = 1.0f / lacc[r];
        int row = q0 + w * 32 + (r & 3) + 8 * (r >> 2) + 4 * hf;
#pragma unroll
        for (int dcb = 0; dcb < 4; ++dcb)
            g_q[(size_t)row * DIMC + h * DHD + dcb * 32 + l32] = f2b(of[dcb][r] * iv);
    }
}

extern "C" void kernel_launch(void* const* d_in, const int* in_sizes, int n_in,
                              void* d_out, int out_size, void* d_ws, size_t ws_size,
                              hipStream_t stream) {
    const float* hidden = (const float*)d_in[0];
    const float* fc = (const float*)d_in[1];
    const float* fs = (const float*)d_in[2];
    const float* Wq = (const float*)d_in[3];
    const float* bq = (const float*)d_in[4];
    const float* Wk = (const float*)d_in[5];
    const float* bk = (const float*)d_in[6];
    const float* Wv = (const float*)d_in[7];
    const float* bv = (const float*)d_in[8];
    const float* Wo = (const float*)d_in[9];
    const float* bo = (const float*)d_in[10];
    const float* gq = (const float*)d_in[11];
    const float* gk = (const float*)d_in[12];

    dim3 blk(256);
    conv_h<<<dim3(4096), blk, 0, stream>>>(hidden);
    prep_w<<<dim3(32, 32, 4), blk, 0, stream>>>(Wq, Wk, Wv, Wo);
    gemm_qkv<<<dim3(16, 32, 3), blk, 0, stream>>>(bq, bk, bv);
    rmsnorm_rope<<<dim3(SEQ, 2), blk, 0, stream>>>(gq, gk, fc, fs);
    transpose_v<<<dim3(64, 2, NH), blk, 0, stream>>>();
    attn_k<<<dim3(32, NH), blk, 0, stream>>>();
    gemm_o<<<dim3(16, 32), blk, 0, stream>>>(bo, (float*)d_out);
}